// Round 1
// baseline (410.614 us; speedup 1.0000x reference)
//
#include <hip/hip_runtime.h>
#include <hip/hip_bf16.h>
#include <stdint.h>

typedef float  f32x4  __attribute__((ext_vector_type(4)));
typedef short  bf16x8 __attribute__((ext_vector_type(8)));
typedef short  bf16x4 __attribute__((ext_vector_type(4)));

#define C_IN   384
#define C_OUT  384
#define Hdim   56
#define Wdim   56
#define HWsz   3136
#define KC     32      // channels (K) per chunk = one MFMA K-step
#define NCHUNK 12      // 384/32
#define LDSS   40      // bf16 elems per pixel row in LDS (80 B, 16B-aligned, non-pow2)
#define NOSUB  24      // 384/16 o-subtiles

__device__ __forceinline__ short f2bf(float f) {
    union { float f; uint32_t u; } v; v.f = f;
    uint32_t u = v.u + (0x7FFFu + ((v.u >> 16) & 1u));   // RNE
    return (short)(u >> 16);
}

// Repack w_pw (fp32 [o][c]) into fragment-ordered bf16:
// flat idx = ((cblk*24 + osub)*64 + lane)*8 + j
// value    = bf16( w_pw[ (osub*16 + (lane&15)) * 384 + cblk*32 + (lane>>4)*8 + j ] )
__global__ void prep_w_kernel(const float* __restrict__ wpw, short* __restrict__ apre) {
    int idx = blockIdx.x * 256 + threadIdx.x;
    if (idx >= C_OUT * C_IN) return;
    int j    = idx & 7;
    int lane = (idx >> 3) & 63;
    int osub = (idx >> 9) % NOSUB;
    int cblk = idx / (NOSUB * 512);
    int o = osub * 16 + (lane & 15);
    int c = cblk * KC + (lane >> 4) * 8 + j;
    apre[idx] = f2bf(wpw[o * C_IN + c]);
}

// One block per (h, n): computes y[n, 0..383, h, 0..55].
// 8 waves; wave w owns o in [48w, 48w+48) (3 o-subtiles) x 64 pixels (4 pix-subtiles).
__global__ __launch_bounds__(512) void fused_dwpw_kernel(
    const float* __restrict__ x, const float* __restrict__ wdw,
    const short* __restrict__ apre, float* __restrict__ y) {

    __shared__ __align__(16) short dw_lds[64 * LDSS];   // 5120 B

    const int h    = blockIdx.x;
    const int n    = blockIdx.y;
    const int tid  = (int)threadIdx.x;
    const int wave = tid >> 6;
    const int lane = tid & 63;
    const int col  = lane & 15;   // pix-within-subtile / o-row within subtile for C
    const int kb   = lane >> 4;   // k-block (0..3)

    f32x4 acc[3][4];
#pragma unroll
    for (int m = 0; m < 3; ++m)
#pragma unroll
        for (int p = 0; p < 4; ++p) acc[m][p] = (f32x4)0.f;

    const float* xn = x + (size_t)n * C_IN * HWsz;

    for (int ch = 0; ch < NCHUNK; ++ch) {
        // ---- depthwise: wave handles channels c_local = wave*4 + q, lane = pixel ----
        short dwv[4];
#pragma unroll
        for (int q = 0; q < 4; ++q) {
            const int c = ch * KC + wave * 4 + q;
            const float* xc = xn + (size_t)c * HWsz;
            const float* wk = wdw + c * 9;
            float a0 = 0.f;
#pragma unroll
            for (int r = 0; r < 3; ++r) {
                const int hh = h + r - 1;
                float xv = 0.f;
                if (hh >= 0 && hh < Hdim && lane < Wdim) xv = xc[hh * Wdim + lane];
                float lf = __shfl_up(xv, 1);
                if (lane == 0) lf = 0.f;               // w=0 left tap = padding
                float rt = __shfl_down(xv, 1);         // lane55 gets lane56 which is 0
                a0 = fmaf(wk[r * 3 + 0], lf, a0);
                a0 = fmaf(wk[r * 3 + 1], xv, a0);
                a0 = fmaf(wk[r * 3 + 2], rt, a0);
            }
            if (lane >= Wdim) a0 = 0.f;                // pad pixels 56..63
            dwv[q] = f2bf(a0);
        }

        __syncthreads();   // previous chunk's B reads done before overwrite
        {
            bf16x4 pk; pk[0] = dwv[0]; pk[1] = dwv[1]; pk[2] = dwv[2]; pk[3] = dwv[3];
            *reinterpret_cast<bf16x4*>(&dw_lds[lane * LDSS + wave * 4]) = pk;
        }
        __syncthreads();   // dw tile visible

        // ---- GEMM: 12 MFMA per wave per chunk ----
        bf16x8 afr[3], bfr[4];
#pragma unroll
        for (int m = 0; m < 3; ++m) {
            const int osub = wave * 3 + m;
            afr[m] = *reinterpret_cast<const bf16x8*>(
                apre + (((ch * NOSUB + osub) * 64 + lane) << 3));
        }
#pragma unroll
        for (int p = 0; p < 4; ++p) {
            bfr[p] = *reinterpret_cast<const bf16x8*>(
                &dw_lds[(p * 16 + col) * LDSS + kb * 8]);
        }
#pragma unroll
        for (int m = 0; m < 3; ++m)
#pragma unroll
            for (int p = 0; p < 4; ++p)
                acc[m][p] = __builtin_amdgcn_mfma_f32_16x16x32_bf16(
                    afr[m], bfr[p], acc[m][p], 0, 0, 0);
    }

    // ---- epilogue: D row = o = wave*48 + m*16 + kb*4 + reg ; col = pix = p*16 + col ----
#pragma unroll
    for (int p = 0; p < 4; ++p) {
        const int pix = p * 16 + col;
        if (pix >= Wdim) continue;
#pragma unroll
        for (int m = 0; m < 3; ++m) {
            const int o0 = wave * 48 + m * 16 + kb * 4;
            float* yp = y + ((size_t)(n * C_OUT + o0)) * HWsz + h * Wdim + pix;
#pragma unroll
            for (int r = 0; r < 4; ++r) yp[(size_t)r * HWsz] = acc[m][p][r];
        }
    }
}

extern "C" void kernel_launch(void* const* d_in, const int* in_sizes, int n_in,
                              void* d_out, int out_size, void* d_ws, size_t ws_size,
                              hipStream_t stream) {
    const float* x   = (const float*)d_in[0];
    const float* wdw = (const float*)d_in[1];
    const float* wpw = (const float*)d_in[2];
    float* y = (float*)d_out;
    short* apre = (short*)d_ws;   // 147456 bf16 = 294912 B

    hipLaunchKernelGGL(prep_w_kernel, dim3((C_OUT * C_IN + 255) / 256), dim3(256),
                       0, stream, wpw, apre);
    hipLaunchKernelGGL(fused_dwpw_kernel, dim3(Hdim, 32), dim3(512),
                       0, stream, x, wdw, apre, y);
}

// Round 2
// 238.392 us; speedup vs baseline: 1.7224x; 1.7224x over previous
//
#include <hip/hip_runtime.h>
#include <hip/hip_bf16.h>
#include <stdint.h>

typedef float  f32x4  __attribute__((ext_vector_type(4)));
typedef short  bf16x8 __attribute__((ext_vector_type(8)));
typedef short  bf16x4 __attribute__((ext_vector_type(4)));

#define C_IN   384
#define C_OUT  384
#define Hdim   56
#define Wdim   56
#define HWsz   3136
#define KC     32
#define NCHUNK 12
#define NOSUB  24      // 384/16 o-subtiles
#define HB     8       // rows per depthwise block

__device__ __forceinline__ short f2bf(float f) {
    union { float f; uint32_t u; } v; v.f = f;
    uint32_t u = v.u + (0x7FFFu + ((v.u >> 16) & 1u));   // RNE
    return (short)(u >> 16);
}

// ---------------- W prepack (shared by both paths) ----------------
// flat idx = ((cblk*24 + osub)*64 + lane)*8 + j
// value    = bf16( w_pw[ (osub*16 + (lane&15)) * 384 + cblk*32 + (lane>>4)*8 + j ] )
__global__ void prep_w_kernel(const float* __restrict__ wpw, short* __restrict__ apre) {
    int idx = blockIdx.x * 256 + threadIdx.x;
    if (idx >= C_OUT * C_IN) return;
    int j    = idx & 7;
    int lane = (idx >> 3) & 63;
    int osub = (idx >> 9) % NOSUB;
    int cblk = idx / (NOSUB * 512);
    int o = osub * 16 + (lane & 15);
    int c = cblk * KC + (lane >> 4) * 8 + j;
    apre[idx] = f2bf(wpw[o * C_IN + c]);
}

// ---------------- Depthwise: x (fp32 NCHW) -> dw_ws (bf16 [n][pix][c]) ----------------
// grid (7 hb, 12 cg, 32 n), 256 threads. Wave handles 8 channels x 8 output rows.
__global__ __launch_bounds__(256) void dw_kernel(
    const float* __restrict__ x, const float* __restrict__ wdw,
    short* __restrict__ dwws) {

    const int hb   = blockIdx.x;
    const int cg   = blockIdx.y;
    const int n    = blockIdx.z;
    const int wave = (int)threadIdx.x >> 6;
    const int lane = (int)threadIdx.x & 63;

    const int c0  = cg * 32 + wave * 8;
    const int c0u = __builtin_amdgcn_readfirstlane(c0);
    const float* wp = wdw + c0u * 9;

    float wk[8][9];
#pragma unroll
    for (int q = 0; q < 8; ++q)
#pragma unroll
        for (int t = 0; t < 9; ++t) wk[q][t] = wp[q * 9 + t];

    const float* xb = x + ((size_t)n * C_IN + c0) * HWsz;

    // rolling window: win[slot][ch][lf/mid/rt]
    float win[3][8][3];

    auto loadrow = [&](int slot, int hh) {
#pragma unroll
        for (int q = 0; q < 8; ++q) {
            float v = 0.f;
            if (hh >= 0 && hh < Hdim && lane < Wdim)
                v = xb[(size_t)q * HWsz + hh * Wdim + lane];
            float lf = __shfl_up(v, 1);
            if (lane == 0) lf = 0.f;
            float rt = __shfl_down(v, 1);   // lane55 pulls lane56 which loaded 0
            win[slot][q][0] = lf; win[slot][q][1] = v; win[slot][q][2] = rt;
        }
    };

    loadrow(0, hb * HB - 1);
    loadrow(1, hb * HB);

#pragma unroll
    for (int r = 0; r < HB; ++r) {
        loadrow((r + 2) % 3, hb * HB + r + 1);

        bf16x8 v8;
#pragma unroll
        for (int q = 0; q < 8; ++q) {
            const int sm = r % 3, s0 = (r + 1) % 3, sp = (r + 2) % 3;
            float a = 0.f;
            a = fmaf(wk[q][0], win[sm][q][0], a);
            a = fmaf(wk[q][1], win[sm][q][1], a);
            a = fmaf(wk[q][2], win[sm][q][2], a);
            a = fmaf(wk[q][3], win[s0][q][0], a);
            a = fmaf(wk[q][4], win[s0][q][1], a);
            a = fmaf(wk[q][5], win[s0][q][2], a);
            a = fmaf(wk[q][6], win[sp][q][0], a);
            a = fmaf(wk[q][7], win[sp][q][1], a);
            a = fmaf(wk[q][8], win[sp][q][2], a);
            v8[q] = f2bf(a);
        }
        if (lane < Wdim) {
            const int pix = (hb * HB + r) * Wdim + lane;
            *reinterpret_cast<bf16x8*>(dwws + ((size_t)n * HWsz + pix) * C_IN + c0) = v8;
        }
    }
}

// ---------------- Pointwise GEMM: y[n][o][pix] = sum_c W[o][c] * dw[n][pix][c] ----------------
// grid (49 pixel-blocks, 32 n), 256 threads (4 waves). Wave owns 96 o x 64 pix.
// No LDS, no barriers: A from prepacked W (L2), B direct 16B global loads.
__global__ __launch_bounds__(256) void pw_kernel(
    const short* __restrict__ apre, const short* __restrict__ dwws,
    float* __restrict__ y) {

    const int pb   = blockIdx.x;
    const int n    = blockIdx.y;
    const int wave = (int)threadIdx.x >> 6;
    const int lane = (int)threadIdx.x & 63;
    const int col  = lane & 15;
    const int kb   = lane >> 4;

    f32x4 acc[6][4];
#pragma unroll
    for (int m = 0; m < 6; ++m)
#pragma unroll
        for (int p = 0; p < 4; ++p) acc[m][p] = (f32x4)0.f;

    const short* bb = dwws + ((size_t)n * HWsz + pb * 64) * C_IN;

#pragma unroll 2
    for (int ch = 0; ch < NCHUNK; ++ch) {
        bf16x8 af[6], bf[4];
#pragma unroll
        for (int m = 0; m < 6; ++m)
            af[m] = *reinterpret_cast<const bf16x8*>(
                apre + (((ch * NOSUB + wave * 6 + m) * 64 + lane) << 3));
#pragma unroll
        for (int p = 0; p < 4; ++p)
            bf[p] = *reinterpret_cast<const bf16x8*>(
                bb + (size_t)(p * 16 + col) * C_IN + ch * KC + kb * 8);
#pragma unroll
        for (int m = 0; m < 6; ++m)
#pragma unroll
            for (int p = 0; p < 4; ++p)
                acc[m][p] = __builtin_amdgcn_mfma_f32_16x16x32_bf16(
                    af[m], bf[p], acc[m][p], 0, 0, 0);
    }

#pragma unroll
    for (int m = 0; m < 6; ++m) {
        const int o = wave * 96 + m * 16 + kb * 4;
        float* yo = y + ((size_t)(n * C_OUT + o)) * HWsz + pb * 64;
#pragma unroll
        for (int p = 0; p < 4; ++p) {
            const int pix = p * 16 + col;
#pragma unroll
            for (int r = 0; r < 4; ++r) yo[(size_t)r * HWsz + pix] = acc[m][p][r];
        }
    }
}

// ---------------- Fallback fused kernel (round-1, correct but slow) ----------------
#define LDSS 40
__global__ __launch_bounds__(512) void fused_dwpw_kernel(
    const float* __restrict__ x, const float* __restrict__ wdw,
    const short* __restrict__ apre, float* __restrict__ y) {

    __shared__ __align__(16) short dw_lds[64 * LDSS];

    const int h    = blockIdx.x;
    const int n    = blockIdx.y;
    const int tid  = (int)threadIdx.x;
    const int wave = tid >> 6;
    const int lane = tid & 63;
    const int col  = lane & 15;
    const int kb   = lane >> 4;

    f32x4 acc[3][4];
#pragma unroll
    for (int m = 0; m < 3; ++m)
#pragma unroll
        for (int p = 0; p < 4; ++p) acc[m][p] = (f32x4)0.f;

    const float* xn = x + (size_t)n * C_IN * HWsz;

    for (int ch = 0; ch < NCHUNK; ++ch) {
        short dwv[4];
#pragma unroll
        for (int q = 0; q < 4; ++q) {
            const int c = ch * KC + wave * 4 + q;
            const float* xc = xn + (size_t)c * HWsz;
            const float* wkp = wdw + c * 9;
            float a0 = 0.f;
#pragma unroll
            for (int r = 0; r < 3; ++r) {
                const int hh = h + r - 1;
                float xv = 0.f;
                if (hh >= 0 && hh < Hdim && lane < Wdim) xv = xc[hh * Wdim + lane];
                float lf = __shfl_up(xv, 1);
                if (lane == 0) lf = 0.f;
                float rt = __shfl_down(xv, 1);
                a0 = fmaf(wkp[r * 3 + 0], lf, a0);
                a0 = fmaf(wkp[r * 3 + 1], xv, a0);
                a0 = fmaf(wkp[r * 3 + 2], rt, a0);
            }
            if (lane >= Wdim) a0 = 0.f;
            dwv[q] = f2bf(a0);
        }

        __syncthreads();
        {
            bf16x4 pk; pk[0] = dwv[0]; pk[1] = dwv[1]; pk[2] = dwv[2]; pk[3] = dwv[3];
            *reinterpret_cast<bf16x4*>(&dw_lds[lane * LDSS + wave * 4]) = pk;
        }
        __syncthreads();

        bf16x8 afr[3], bfr[4];
#pragma unroll
        for (int m = 0; m < 3; ++m)
            afr[m] = *reinterpret_cast<const bf16x8*>(
                apre + (((ch * NOSUB + wave * 3 + m) * 64 + lane) << 3));
#pragma unroll
        for (int p = 0; p < 4; ++p)
            bfr[p] = *reinterpret_cast<const bf16x8*>(
                &dw_lds[(p * 16 + col) * LDSS + kb * 8]);
#pragma unroll
        for (int m = 0; m < 3; ++m)
#pragma unroll
            for (int p = 0; p < 4; ++p)
                acc[m][p] = __builtin_amdgcn_mfma_f32_16x16x32_bf16(
                    afr[m], bfr[p], acc[m][p], 0, 0, 0);
    }

#pragma unroll
    for (int p = 0; p < 4; ++p) {
        const int pix = p * 16 + col;
        if (pix >= Wdim) continue;
#pragma unroll
        for (int m = 0; m < 3; ++m) {
            const int o0 = wave * 48 + m * 16 + kb * 4;
            float* yp = y + ((size_t)(n * C_OUT + o0)) * HWsz + h * Wdim + pix;
#pragma unroll
            for (int r = 0; r < 4; ++r) yp[(size_t)r * HWsz] = acc[m][p][r];
        }
    }
}

extern "C" void kernel_launch(void* const* d_in, const int* in_sizes, int n_in,
                              void* d_out, int out_size, void* d_ws, size_t ws_size,
                              hipStream_t stream) {
    const float* x   = (const float*)d_in[0];
    const float* wdw = (const float*)d_in[1];
    const float* wpw = (const float*)d_in[2];
    float* y = (float*)d_out;

    short* apre = (short*)d_ws;                       // 294912 B
    const size_t DW_OFF   = 512 * 1024;
    const size_t DW_BYTES = (size_t)32 * HWsz * C_IN * 2;   // 77,070,336 B

    hipLaunchKernelGGL(prep_w_kernel, dim3((C_OUT * C_IN + 255) / 256), dim3(256),
                       0, stream, wpw, apre);

    if (ws_size >= DW_OFF + DW_BYTES) {
        short* dwws = (short*)((char*)d_ws + DW_OFF);
        hipLaunchKernelGGL(dw_kernel, dim3(Hdim / HB, NCHUNK, 32), dim3(256),
                           0, stream, x, wdw, dwws);
        hipLaunchKernelGGL(pw_kernel, dim3(HWsz / 64, 32), dim3(256),
                           0, stream, apre, dwws, y);
    } else {
        hipLaunchKernelGGL(fused_dwpw_kernel, dim3(Hdim, 32), dim3(512),
                           0, stream, x, wdw, apre, y);
    }
}

// Round 3
// 153.314 us; speedup vs baseline: 2.6783x; 1.5549x over previous
//
#include <hip/hip_runtime.h>
#include <hip/hip_bf16.h>
#include <stdint.h>

typedef float  f32x4  __attribute__((ext_vector_type(4)));
typedef short  bf16x8 __attribute__((ext_vector_type(8)));
typedef short  bf16x4 __attribute__((ext_vector_type(4)));

#define C_IN   384
#define C_OUT  384
#define Hdim   56
#define Wdim   56
#define HWsz   3136
#define KC     32
#define NCHUNK 12
#define NOSUB  24      // 384/16 o-subtiles
#define BSTR   ((size_t)HWsz * KC)   // elems per (n, cblk) slab of dw-ws

__device__ __forceinline__ short f2bf(float f) {
    union { float f; uint32_t u; } v; v.f = f;
    uint32_t u = v.u + (0x7FFFu + ((v.u >> 16) & 1u));   // RNE
    return (short)(u >> 16);
}

// ---------------- W prepack ----------------
// flat idx = ((cblk*24 + osub)*64 + lane)*8 + j
// value    = bf16( w_pw[ (osub*16 + (lane&15)) * 384 + cblk*32 + (lane>>4)*8 + j ] )
__global__ void prep_w_kernel(const float* __restrict__ wpw, short* __restrict__ apre) {
    int idx = blockIdx.x * 256 + threadIdx.x;
    if (idx >= C_OUT * C_IN) return;
    int j    = idx & 7;
    int lane = (idx >> 3) & 63;
    int osub = (idx >> 9) % NOSUB;
    int cblk = idx / (NOSUB * 512);
    int o = osub * 16 + (lane & 15);
    int c = cblk * KC + (lane >> 4) * 8 + j;
    apre[idx] = f2bf(wpw[o * C_IN + c]);
}

// ---------------- Depthwise v3: x (fp32 NCHW) -> dw_ws (bf16 [n][cblk][pix][c32]) -----
// grid (56 rows, 12 cblk, 32 n), 256 threads. Wave = 8 channels x 1 output row.
// All 24 loads issued up front (MLP), no rolling window, weights via uniform s_load.
__global__ __launch_bounds__(256) void dw_kernel(
    const float* __restrict__ x, const float* __restrict__ wdw,
    short* __restrict__ dwws) {

    const int h    = blockIdx.x;
    const int cblk = blockIdx.y;
    const int n    = blockIdx.z;
    const int wave = (int)threadIdx.x >> 6;
    const int lane = (int)threadIdx.x & 63;

    const int c0  = cblk * KC + wave * 8;
    const int c0u = __builtin_amdgcn_readfirstlane(c0);

    const float* xb = x + ((size_t)n * C_IN + c0u) * HWsz;

    // ---- issue ALL loads first: 8 channels x 3 rows, 4B/lane coalesced ----
    float v[8][3];
#pragma unroll
    for (int q = 0; q < 8; ++q) {
#pragma unroll
        for (int d = 0; d < 3; ++d) {
            const int hh = h + d - 1;
            const bool ok = (hh >= 0) && (hh < Hdim) && (lane < Wdim);
            v[q][d] = ok ? xb[(size_t)q * HWsz + hh * Wdim + lane] : 0.f;
        }
    }

    // ---- weights: uniform address -> scalar loads ----
    const float* wp = wdw + c0u * 9;
    float wk[8][9];
#pragma unroll
    for (int q = 0; q < 8; ++q)
#pragma unroll
        for (int t = 0; t < 9; ++t) wk[q][t] = wp[q * 9 + t];

    // ---- compute: halo via shfl at use time ----
    bf16x8 pk;
#pragma unroll
    for (int q = 0; q < 8; ++q) {
        float a = 0.f;
#pragma unroll
        for (int d = 0; d < 3; ++d) {
            const float c_ = v[q][d];
            float lf = __shfl_up(c_, 1);
            if (lane == 0) lf = 0.f;
            const float rt = __shfl_down(c_, 1);   // lane55 pulls lane56 which loaded 0
            a = fmaf(wk[q][d * 3 + 0], lf, a);
            a = fmaf(wk[q][d * 3 + 1], c_, a);
            a = fmaf(wk[q][d * 3 + 2], rt, a);
        }
        pk[q] = f2bf(a);
    }

    if (lane < Wdim) {
        const size_t off = (((size_t)n * NCHUNK + cblk) * HWsz + h * Wdim + lane) * KC
                         + wave * 8;
        *reinterpret_cast<bf16x8*>(dwws + off) = pk;
    }
}

// ---------------- Pointwise GEMM v2: y[n][o][pix] = sum_c W[o][c]*dw[n][pix][c] -------
// grid (49 pixel-blocks, 32 n), 256 threads (4 waves). Wave owns 96 o x 64 pix.
// B layout [n][cblk][pix][c32]: each bf[p] wave-load is 1KB contiguous.
// B register double-buffered one chunk ahead (bufs[2][4], fully unrolled).
__global__ __launch_bounds__(256, 3) void pw_kernel(
    const short* __restrict__ apre, const short* __restrict__ dwws,
    float* __restrict__ y) {

    const int pb   = blockIdx.x;
    const int n    = blockIdx.y;
    const int wave = (int)threadIdx.x >> 6;
    const int lane = (int)threadIdx.x & 63;
    const int col  = lane & 15;
    const int kb   = lane >> 4;

    f32x4 acc[6][4];
#pragma unroll
    for (int m = 0; m < 6; ++m)
#pragma unroll
        for (int p = 0; p < 4; ++p) acc[m][p] = (f32x4)0.f;

    // per-lane B base: ((n*12 + ch)*HWsz + pb*64 + p*16 + col)*32 + kb*8
    const short* bb = dwws + (size_t)n * NCHUNK * BSTR
                    + ((size_t)pb * 64 + col) * KC + kb * 8;

    bf16x8 bufs[2][4];
#pragma unroll
    for (int p = 0; p < 4; ++p)
        bufs[0][p] = *reinterpret_cast<const bf16x8*>(bb + (size_t)p * (16 * KC));

#pragma unroll
    for (int ch = 0; ch < NCHUNK; ++ch) {
        const int cur = ch & 1, nxt = cur ^ 1;
        if (ch < NCHUNK - 1) {
#pragma unroll
            for (int p = 0; p < 4; ++p)
                bufs[nxt][p] = *reinterpret_cast<const bf16x8*>(
                    bb + (size_t)(ch + 1) * BSTR + (size_t)p * (16 * KC));
        }
#pragma unroll
        for (int m = 0; m < 6; ++m) {
            const bf16x8 af = *reinterpret_cast<const bf16x8*>(
                apre + (((ch * NOSUB + wave * 6 + m) * 64 + lane) << 3));
#pragma unroll
            for (int p = 0; p < 4; ++p)
                acc[m][p] = __builtin_amdgcn_mfma_f32_16x16x32_bf16(
                    af, bufs[cur][p], acc[m][p], 0, 0, 0);
        }
    }

#pragma unroll
    for (int m = 0; m < 6; ++m) {
        const int o = wave * 96 + m * 16 + kb * 4;
        float* yo = y + ((size_t)(n * C_OUT + o)) * HWsz + pb * 64;
#pragma unroll
        for (int p = 0; p < 4; ++p) {
            const int pix = p * 16 + col;
#pragma unroll
            for (int r = 0; r < 4; ++r) yo[(size_t)r * HWsz + pix] = acc[m][p][r];
        }
    }
}

// ---------------- Fallback fused kernel (round-1, correct but slow) ----------------
#define LDSS 40
__global__ __launch_bounds__(512) void fused_dwpw_kernel(
    const float* __restrict__ x, const float* __restrict__ wdw,
    const short* __restrict__ apre, float* __restrict__ y) {

    __shared__ __align__(16) short dw_lds[64 * LDSS];

    const int h    = blockIdx.x;
    const int n    = blockIdx.y;
    const int tid  = (int)threadIdx.x;
    const int wave = tid >> 6;
    const int lane = tid & 63;
    const int col  = lane & 15;
    const int kb   = lane >> 4;

    f32x4 acc[3][4];
#pragma unroll
    for (int m = 0; m < 3; ++m)
#pragma unroll
        for (int p = 0; p < 4; ++p) acc[m][p] = (f32x4)0.f;

    const float* xn = x + (size_t)n * C_IN * HWsz;

    for (int ch = 0; ch < NCHUNK; ++ch) {
        short dwv[4];
#pragma unroll
        for (int q = 0; q < 4; ++q) {
            const int c = ch * KC + wave * 4 + q;
            const float* xc = xn + (size_t)c * HWsz;
            const float* wkp = wdw + c * 9;
            float a0 = 0.f;
#pragma unroll
            for (int r = 0; r < 3; ++r) {
                const int hh = h + r - 1;
                float xv = 0.f;
                if (hh >= 0 && hh < Hdim && lane < Wdim) xv = xc[hh * Wdim + lane];
                float lf = __shfl_up(xv, 1);
                if (lane == 0) lf = 0.f;
                float rt = __shfl_down(xv, 1);
                a0 = fmaf(wkp[r * 3 + 0], lf, a0);
                a0 = fmaf(wkp[r * 3 + 1], xv, a0);
                a0 = fmaf(wkp[r * 3 + 2], rt, a0);
            }
            if (lane >= Wdim) a0 = 0.f;
            dwv[q] = f2bf(a0);
        }

        __syncthreads();
        {
            bf16x4 pk2; pk2[0] = dwv[0]; pk2[1] = dwv[1]; pk2[2] = dwv[2]; pk2[3] = dwv[3];
            *reinterpret_cast<bf16x4*>(&dw_lds[lane * LDSS + wave * 4]) = pk2;
        }
        __syncthreads();

        bf16x8 afr[3], bfr[4];
#pragma unroll
        for (int m = 0; m < 3; ++m)
            afr[m] = *reinterpret_cast<const bf16x8*>(
                apre + (((ch * NOSUB + wave * 3 + m) * 64 + lane) << 3));
#pragma unroll
        for (int p = 0; p < 4; ++p)
            bfr[p] = *reinterpret_cast<const bf16x8*>(
                &dw_lds[(p * 16 + col) * LDSS + kb * 8]);
#pragma unroll
        for (int m = 0; m < 3; ++m)
#pragma unroll
            for (int p = 0; p < 4; ++p)
                acc[m][p] = __builtin_amdgcn_mfma_f32_16x16x32_bf16(
                    afr[m], bfr[p], acc[m][p], 0, 0, 0);
    }

#pragma unroll
    for (int p = 0; p < 4; ++p) {
        const int pix = p * 16 + col;
        if (pix >= Wdim) continue;
#pragma unroll
        for (int m = 0; m < 3; ++m) {
            const int o0 = wave * 48 + m * 16 + kb * 4;
            float* yp = y + ((size_t)(n * C_OUT + o0)) * HWsz + h * Wdim + pix;
#pragma unroll
            for (int r = 0; r < 4; ++r) yp[(size_t)r * HWsz] = acc[m][p][r];
        }
    }
}

extern "C" void kernel_launch(void* const* d_in, const int* in_sizes, int n_in,
                              void* d_out, int out_size, void* d_ws, size_t ws_size,
                              hipStream_t stream) {
    const float* x   = (const float*)d_in[0];
    const float* wdw = (const float*)d_in[1];
    const float* wpw = (const float*)d_in[2];
    float* y = (float*)d_out;

    short* apre = (short*)d_ws;                       // 294912 B
    const size_t DW_OFF   = 512 * 1024;
    const size_t DW_BYTES = (size_t)32 * HWsz * C_IN * 2;   // 77,070,336 B

    hipLaunchKernelGGL(prep_w_kernel, dim3((C_OUT * C_IN + 255) / 256), dim3(256),
                       0, stream, wpw, apre);

    if (ws_size >= DW_OFF + DW_BYTES) {
        short* dwws = (short*)((char*)d_ws + DW_OFF);
        hipLaunchKernelGGL(dw_kernel, dim3(Hdim, NCHUNK, 32), dim3(256),
                           0, stream, x, wdw, dwws);
        hipLaunchKernelGGL(pw_kernel, dim3(HWsz / 64, 32), dim3(256),
                           0, stream, apre, dwws, y);
    } else {
        hipLaunchKernelGGL(fused_dwpw_kernel, dim3(Hdim, 32), dim3(512),
                           0, stream, x, wdw, apre, y);
    }
}

// Round 4
// 126.216 us; speedup vs baseline: 3.2533x; 1.2147x over previous
//
#include <hip/hip_runtime.h>
#include <hip/hip_bf16.h>
#include <stdint.h>

typedef float  f32x4  __attribute__((ext_vector_type(4)));
typedef short  bf16x8 __attribute__((ext_vector_type(8)));
typedef short  bf16x4 __attribute__((ext_vector_type(4)));

#define C_IN   384
#define C_OUT  384
#define Hdim   56
#define Wdim   56
#define HWsz   3136
#define KC     32
#define NCHUNK 12
#define NOSUB  24
#define BSTR   ((size_t)HWsz * KC)   // elems per (n, cblk) slab of dw-ws
#define RB     4                     // output rows per wave (dw)
#define NRB    (Hdim / RB)           // 14
#define NBLKDW (NRB * NCHUNK * 32)   // 5376, %8==0

__device__ __forceinline__ short f2bf(float f) {
    union { float f; uint32_t u; } v; v.f = f;
    uint32_t u = v.u + (0x7FFFu + ((v.u >> 16) & 1u));   // RNE
    return (short)(u >> 16);
}

// ---------------- W prepack ----------------
// flat idx = ((cblk*24 + osub)*64 + lane)*8 + j
// value    = bf16( w_pw[ (osub*16 + (lane&15)) * 384 + cblk*32 + (lane>>4)*8 + j ] )
__global__ void prep_w_kernel(const float* __restrict__ wpw, short* __restrict__ apre) {
    int idx = blockIdx.x * 256 + threadIdx.x;
    if (idx >= C_OUT * C_IN) return;
    int j    = idx & 7;
    int lane = (idx >> 3) & 63;
    int osub = (idx >> 9) % NOSUB;
    int cblk = idx / (NOSUB * 512);
    int o = osub * 16 + (lane & 15);
    int c = cblk * KC + (lane >> 4) * 8 + j;
    apre[idx] = f2bf(wpw[o * C_IN + c]);
}

// ---------------- Depthwise v5: x (fp32 NCHW) -> dw_ws (bf16 [n][cblk][pix][c32]) -----
// Wave = 8 channels x 4 output rows (6 input rows, halo factor 1.5x).
// 48 loads issued up front; XCD-chunked block swizzle makes halo re-reads L2-local.
__global__ __launch_bounds__(256) void dw_kernel(
    const float* __restrict__ x, const float* __restrict__ wdw,
    short* __restrict__ dwws) {

    // bijective chunked XCD swizzle: XCD k executes a contiguous range of l
    const int p  = (int)blockIdx.x;
    const int l  = (p & 7) * (NBLKDW / 8) + (p >> 3);
    const int rb   = l % NRB;
    const int cblk = (l / NRB) % NCHUNK;
    const int n    = l / (NRB * NCHUNK);

    const int wave = (int)threadIdx.x >> 6;
    const int lane = (int)threadIdx.x & 63;
    const int c0u  = __builtin_amdgcn_readfirstlane(cblk * KC + wave * 8);
    const int h0   = rb * RB;

    const float* xb = x + ((size_t)n * C_IN + c0u) * HWsz;

    // ---- issue ALL 48 loads first (8 ch x 6 rows, 4B/lane coalesced) ----
    float v[8][RB + 2];
#pragma unroll
    for (int q = 0; q < 8; ++q)
#pragma unroll
        for (int d = 0; d < RB + 2; ++d) {
            const int hh = h0 + d - 1;
            const bool ok = (hh >= 0) && (hh < Hdim) && (lane < Wdim);
            v[q][d] = ok ? xb[(size_t)q * HWsz + hh * Wdim + lane] : 0.f;
        }

    // ---- weights: uniform address -> scalar loads ----
    const float* wp = wdw + c0u * 9;
    float wk[8][9];
#pragma unroll
    for (int q = 0; q < 8; ++q)
#pragma unroll
        for (int t = 0; t < 9; ++t) wk[q][t] = wp[q * 9 + t];

    // ---- compute: halo via shfl (one pair per loaded row) ----
    bf16x8 pk[RB];
#pragma unroll
    for (int q = 0; q < 8; ++q) {
        float lf[RB + 2], rt[RB + 2];
#pragma unroll
        for (int d = 0; d < RB + 2; ++d) {
            float u = __shfl_up(v[q][d], 1);
            if (lane == 0) u = 0.f;
            lf[d] = u;
            rt[d] = __shfl_down(v[q][d], 1);   // lane55 pulls lane56 which loaded 0
        }
#pragma unroll
        for (int r = 0; r < RB; ++r) {
            float a = 0.f;
#pragma unroll
            for (int d = 0; d < 3; ++d) {
                a = fmaf(wk[q][d * 3 + 0], lf[r + d], a);
                a = fmaf(wk[q][d * 3 + 1], v[q][r + d], a);
                a = fmaf(wk[q][d * 3 + 2], rt[r + d], a);
            }
            pk[r][q] = f2bf(a);
        }
    }

    if (lane < Wdim) {
#pragma unroll
        for (int r = 0; r < RB; ++r) {
            const size_t off = (((size_t)n * NCHUNK + cblk) * HWsz
                               + (h0 + r) * Wdim + lane) * KC + wave * 8;
            *reinterpret_cast<bf16x8*>(dwws + off) = pk[r];
        }
    }
}

// ---------------- Pointwise GEMM v3: y[n][o][pix] = sum_c W[o][c]*dw[n][pix][c] -------
// grid (49 pixel-blocks, 32 n), 256 threads (4 waves). Wave owns 96 o x 64 pix.
// B layout [n][cblk][pix][c32]: each bf load 16B/lane contiguous. Prefetch depth 2.
__global__ __launch_bounds__(256, 3) void pw_kernel(
    const short* __restrict__ apre, const short* __restrict__ dwws,
    float* __restrict__ y) {

    const int pb   = blockIdx.x;
    const int n    = blockIdx.y;
    const int wave = (int)threadIdx.x >> 6;
    const int lane = (int)threadIdx.x & 63;
    const int col  = lane & 15;
    const int kb   = lane >> 4;

    f32x4 acc[6][4];
#pragma unroll
    for (int m = 0; m < 6; ++m)
#pragma unroll
        for (int p = 0; p < 4; ++p) acc[m][p] = (f32x4)0.f;

    // per-lane B base: ((n*12 + ch)*HWsz + pb*64 + p*16 + col)*32 + kb*8
    const short* bb = dwws + (size_t)n * NCHUNK * BSTR
                    + ((size_t)pb * 64 + col) * KC + kb * 8;

    bf16x8 bufs[3][4];
#pragma unroll
    for (int p = 0; p < 4; ++p) {
        bufs[0][p] = *reinterpret_cast<const bf16x8*>(bb + (size_t)p * (16 * KC));
        bufs[1][p] = *reinterpret_cast<const bf16x8*>(bb + BSTR + (size_t)p * (16 * KC));
    }

#pragma unroll
    for (int ch = 0; ch < NCHUNK; ++ch) {
        if (ch + 2 < NCHUNK) {
#pragma unroll
            for (int p = 0; p < 4; ++p)
                bufs[(ch + 2) % 3][p] = *reinterpret_cast<const bf16x8*>(
                    bb + (size_t)(ch + 2) * BSTR + (size_t)p * (16 * KC));
        }
#pragma unroll
        for (int m = 0; m < 6; ++m) {
            const bf16x8 af = *reinterpret_cast<const bf16x8*>(
                apre + (((ch * NOSUB + wave * 6 + m) * 64 + lane) << 3));
#pragma unroll
            for (int p = 0; p < 4; ++p)
                acc[m][p] = __builtin_amdgcn_mfma_f32_16x16x32_bf16(
                    af, bufs[ch % 3][p], acc[m][p], 0, 0, 0);
        }
    }

#pragma unroll
    for (int m = 0; m < 6; ++m) {
        const int o = wave * 96 + m * 16 + kb * 4;
        float* yo = y + ((size_t)(n * C_OUT + o)) * HWsz + pb * 64;
#pragma unroll
        for (int p = 0; p < 4; ++p) {
            const int pix = p * 16 + col;
#pragma unroll
            for (int r = 0; r < 4; ++r) yo[(size_t)r * HWsz + pix] = acc[m][p][r];
        }
    }
}

// ---------------- Fallback fused kernel (round-1, correct but slow) ----------------
#define LDSS 40
__global__ __launch_bounds__(512) void fused_dwpw_kernel(
    const float* __restrict__ x, const float* __restrict__ wdw,
    const short* __restrict__ apre, float* __restrict__ y) {

    __shared__ __align__(16) short dw_lds[64 * LDSS];

    const int h    = blockIdx.x;
    const int n    = blockIdx.y;
    const int tid  = (int)threadIdx.x;
    const int wave = tid >> 6;
    const int lane = tid & 63;
    const int col  = lane & 15;
    const int kb   = lane >> 4;

    f32x4 acc[3][4];
#pragma unroll
    for (int m = 0; m < 3; ++m)
#pragma unroll
        for (int p = 0; p < 4; ++p) acc[m][p] = (f32x4)0.f;

    const float* xn = x + (size_t)n * C_IN * HWsz;

    for (int ch = 0; ch < NCHUNK; ++ch) {
        short dwv[4];
#pragma unroll
        for (int q = 0; q < 4; ++q) {
            const int c = ch * KC + wave * 4 + q;
            const float* xc = xn + (size_t)c * HWsz;
            const float* wkp = wdw + c * 9;
            float a0 = 0.f;
#pragma unroll
            for (int r = 0; r < 3; ++r) {
                const int hh = h + r - 1;
                float xv = 0.f;
                if (hh >= 0 && hh < Hdim && lane < Wdim) xv = xc[hh * Wdim + lane];
                float lf = __shfl_up(xv, 1);
                if (lane == 0) lf = 0.f;
                float rt = __shfl_down(xv, 1);
                a0 = fmaf(wkp[r * 3 + 0], lf, a0);
                a0 = fmaf(wkp[r * 3 + 1], xv, a0);
                a0 = fmaf(wkp[r * 3 + 2], rt, a0);
            }
            if (lane >= Wdim) a0 = 0.f;
            dwv[q] = f2bf(a0);
        }

        __syncthreads();
        {
            bf16x4 pk2; pk2[0] = dwv[0]; pk2[1] = dwv[1]; pk2[2] = dwv[2]; pk2[3] = dwv[3];
            *reinterpret_cast<bf16x4*>(&dw_lds[lane * LDSS + wave * 4]) = pk2;
        }
        __syncthreads();

        bf16x8 afr[3], bfr[4];
#pragma unroll
        for (int m = 0; m < 3; ++m)
            afr[m] = *reinterpret_cast<const bf16x8*>(
                apre + (((ch * NOSUB + wave * 3 + m) * 64 + lane) << 3));
#pragma unroll
        for (int p = 0; p < 4; ++p)
            bfr[p] = *reinterpret_cast<const bf16x8*>(
                &dw_lds[(p * 16 + col) * LDSS + kb * 8]);
#pragma unroll
        for (int m = 0; m < 3; ++m)
#pragma unroll
            for (int p = 0; p < 4; ++p)
                acc[m][p] = __builtin_amdgcn_mfma_f32_16x16x32_bf16(
                    afr[m], bfr[p], acc[m][p], 0, 0, 0);
    }

#pragma unroll
    for (int p = 0; p < 4; ++p) {
        const int pix = p * 16 + col;
        if (pix >= Wdim) continue;
#pragma unroll
        for (int m = 0; m < 3; ++m) {
            const int o0 = wave * 48 + m * 16 + kb * 4;
            float* yp = y + ((size_t)(n * C_OUT + o0)) * HWsz + h * Wdim + pix;
#pragma unroll
            for (int r = 0; r < 4; ++r) yp[(size_t)r * HWsz] = acc[m][p][r];
        }
    }
}

extern "C" void kernel_launch(void* const* d_in, const int* in_sizes, int n_in,
                              void* d_out, int out_size, void* d_ws, size_t ws_size,
                              hipStream_t stream) {
    const float* x   = (const float*)d_in[0];
    const float* wdw = (const float*)d_in[1];
    const float* wpw = (const float*)d_in[2];
    float* y = (float*)d_out;

    short* apre = (short*)d_ws;                       // 294912 B
    const size_t DW_OFF   = 512 * 1024;
    const size_t DW_BYTES = (size_t)32 * HWsz * C_IN * 2;   // 77,070,336 B

    hipLaunchKernelGGL(prep_w_kernel, dim3((C_OUT * C_IN + 255) / 256), dim3(256),
                       0, stream, wpw, apre);

    if (ws_size >= DW_OFF + DW_BYTES) {
        short* dwws = (short*)((char*)d_ws + DW_OFF);
        hipLaunchKernelGGL(dw_kernel, dim3(NBLKDW), dim3(256),
                           0, stream, x, wdw, dwws);
        hipLaunchKernelGGL(pw_kernel, dim3(HWsz / 64, 32), dim3(256),
                           0, stream, apre, dwws, y);
    } else {
        hipLaunchKernelGGL(fused_dwpw_kernel, dim3(Hdim, 32), dim3(512),
                           0, stream, x, wdw, apre, y);
    }
}